// Round 10
// baseline (7538.468 us; speedup 1.0000x reference)
//
#include <hip/hip_runtime.h>

// WeatherLSTM: B=256, T=128, I=64, H=2048, O=24
// R10: all-register GEMM. No LDS staging, no barriers in the k-loop: each wave
// loads MFMA fragments (contiguous 16B/lane) directly from global with plain
// loads (deep outstanding, full L2 rate) into a depth-3 register pipeline.
// 256 blocks x 256 thr (4 waves, 2x2), wave tile 64 rows x 32 pcols,
// mfma_32x32x16. LDS used only for the (R9-proven) epilogue transpose.

#define NB 256
#define NH 2048
#define NI 64
#define NK 2112
#define NPK 8192
#define NSTEPS 151
#define NO 24

typedef __bf16 bf16x8 __attribute__((ext_vector_type(8)));
typedef short short8 __attribute__((ext_vector_type(8)));
typedef float f32x4 __attribute__((ext_vector_type(4)));
typedef float f32x16 __attribute__((ext_vector_type(16)));
typedef unsigned short u16;

__device__ __forceinline__ u16 f2bf(float f) {
  union { float f; unsigned u; } v; v.f = f;
  unsigned r = v.u + 0x7FFFu + ((v.u >> 16) & 1u);  // RNE
  return (u16)(r >> 16);
}

__device__ __forceinline__ float sigmoidf_(float x) { return 1.f / (1.f + __expf(-x)); }
__device__ __forceinline__ float tanhf_(float x) {
  x = fminf(15.f, fmaxf(-15.f, x));
  float e = __expf(2.f * x);
  return (e - 1.f) / (e + 1.f);
}

// ---- pack [Wh;Wx] fp32 [k][4H] -> Wp bf16 [p][k], p = u*4+g
__global__ __launch_bounds__(256) void wl_pack_w(const float* __restrict__ Wx,
                                                 const float* __restrict__ Wh,
                                                 u16* __restrict__ Wp) {
  __shared__ float s[64][65];
  const int j0 = blockIdx.x * 64, k0 = blockIdx.y * 64;
  const int tid = threadIdx.x;
  const int jl = tid & 63, kg = tid >> 6;
#pragma unroll
  for (int it = 0; it < 16; ++it) {
    int kl = it * 4 + kg;
    int k = k0 + kl, j = j0 + jl;
    float v = (k < NH) ? Wh[(size_t)k * NPK + j] : Wx[(size_t)(k - NH) * NPK + j];
    s[kl][jl] = v;
  }
  __syncthreads();
  int j = j0 + jl;
  int p = (j & (NH - 1)) * 4 + (j >> 11);
  short8 v0, v1;
#pragma unroll
  for (int e = 0; e < 8; ++e) {
    v0[e] = (short)f2bf(s[kg * 16 + e][jl]);
    v1[e] = (short)f2bf(s[kg * 16 + 8 + e][jl]);
  }
  short8* dst = (short8*)(Wp + (size_t)p * NK + k0 + kg * 16);
  dst[0] = v0;
  dst[1] = v1;
}

__global__ __launch_bounds__(256) void wl_bsum(const float* __restrict__ bx,
                                               const float* __restrict__ bh,
                                               float* __restrict__ bsum) {
  int p = blockIdx.x * 256 + threadIdx.x;
  int j = (p & 3) * NH + (p >> 2);
  bsum[p] = bx[j] + bh[j];
}

__global__ __launch_bounds__(256) void wl_xall(const float* __restrict__ trains,
                                               const float* __restrict__ dec,
                                               const float* __restrict__ Win,
                                               const float* __restrict__ b_in,
                                               u16* __restrict__ xall) {
  int idx = blockIdx.x * 256 + threadIdx.x;
  int i = idx & 63;
  int b = (idx >> 6) & 255;
  int t = idx >> 14;
  float v;
  if (t < 128) v = trains[((size_t)b * 128 + t) * 64 + i];
  else         v = dec[b * 23 + (t - 128)] * Win[i] + b_in[i];
  xall[idx] = f2bf(v);
}

// ---- one step. 256 blocks x 256 threads (4 waves 2x2). Tile 128 x 64 pcols.
// cs = (bid&7)*16 + ((bid>>3)&15), rh = bid>>7; bid & bid+128 share cs + XCD.
// Wave (wm,wn): rows [b0+wm*64,+64) x pcols [p0+wn*32,+32). All fragments
// loaded straight to VGPRs; depth-3 register pipeline; no k-loop barriers.
__global__ __launch_bounds__(256, 1) void wl_step(const u16* __restrict__ Wpg,
                                                  const float* __restrict__ bsum,
                                                  const u16* __restrict__ xall,
                                                  u16* __restrict__ hcat,  // 2 bufs
                                                  float* __restrict__ c_t, // [u][b]
                                                  float* __restrict__ ypart,
                                                  const float* __restrict__ Wout,
                                                  int t) {
  __shared__ char arena[32768];  // epilogue gtile only

  const int bid = blockIdx.x;
  const int cs = (bid & 7) * 16 + ((bid >> 3) & 15);  // col-slice 0..127
  const int rh = bid >> 7;                            // row half 0/1
  const int p0 = cs * 64, u0 = cs * 16, b0 = rh * 128;

  const int tid = threadIdx.x;
  const int wv = tid >> 6, lane = tid & 63;           // wv 0..3
  const int wm = wv >> 1, wn = wv & 1;
  const int l31 = lane & 31, lh = lane >> 5;
  const int ko = lh * 8;                              // k-offset within k16

  const u16* __restrict__ hin = hcat + (size_t)(t & 1) * NB * NH;
  u16* __restrict__ hout = hcat + (size_t)((t + 1) & 1) * NB * NH;

  // per-lane base pointers
  const u16* const hrow0 = hin + (size_t)(b0 + wm * 64 + l31) * NH;        // + kt*64
  const u16* const hrow1 = hrow0 + (size_t)32 * NH;
  const u16* const xrow0 = xall + ((size_t)t * NB + b0 + wm * 64 + l31) * NI;
  const u16* const xrow1 = xrow0 + 32 * NI;
  const u16* const bcol  = Wpg + (size_t)(p0 + wn * 32 + l31) * NK;        // + kt*64

  f32x16 acc0 = {}, acc1 = {};

  struct LB { bf16x8 a0[4], a1[4], b[4]; };  // 48 VGPR
  LB A, B, C;

  auto load = [&](int kt, LB& L) {
    const u16 *r0, *r1;
    if (kt < 32) { r0 = hrow0 + kt * 64; r1 = hrow1 + kt * 64; }
    else         { r0 = xrow0;           r1 = xrow1; }
    const u16* bp = bcol + kt * 64;
#pragma unroll
    for (int s = 0; s < 4; ++s) {
      L.a0[s] = *(const bf16x8*)(r0 + s * 16 + ko);
      L.a1[s] = *(const bf16x8*)(r1 + s * 16 + ko);
      L.b[s]  = *(const bf16x8*)(bp + s * 16 + ko);
    }
  };
  auto comp = [&](LB& L) {
#pragma unroll
    for (int s = 0; s < 4; ++s) {
      acc0 = __builtin_amdgcn_mfma_f32_32x32x16_bf16(L.a0[s], L.b[s], acc0, 0, 0, 0);
      acc1 = __builtin_amdgcn_mfma_f32_32x32x16_bf16(L.a1[s], L.b[s], acc1, 0, 0, 0);
    }
  };

  load(0, A); load(1, B); load(2, C);
  for (int it = 0; it < 11; ++it) {
    const int kt = it * 3;
    comp(A); if (kt + 3 < 33) load(kt + 3, A);
    comp(B); if (kt + 4 < 33) load(kt + 4, B);
    comp(C); if (kt + 5 < 33) load(kt + 5, C);
  }

  // ---- spill acc -> gtile [col 0..63][chunk(row>>2) 0..31] swizzled, 32KB
  {
    const int col = wn * 32 + l31;
#pragma unroll
    for (int mb = 0; mb < 2; ++mb) {
      const f32x16& a = mb ? acc1 : acc0;
#pragma unroll
      for (int q = 0; q < 4; ++q) {
        f32x4 v = {a[q * 4 + 0], a[q * 4 + 1], a[q * 4 + 2], a[q * 4 + 3]};
        int chunk = wm * 16 + mb * 8 + q * 2 + lh;  // row>>2
        *(f32x4*)(arena + col * 512 + ((chunk ^ (col & 7)) << 4)) = v;
      }
    }
  }
  __syncthreads();

  // ---- gates + state: thread -> (row bl 0..127, unit-group ug of 8 units)
  {
    const int bl = tid & 127, ug = tid >> 7;  // ug 0..1
    const int bg = b0 + bl;
    const bool emit = (t >= 127);
    float yacc = 0.f;
    short8 hv;
#pragma unroll
    for (int j = 0; j < 8; ++j) {
      int ul = ug * 8 + j;                 // local unit 0..15
      float g[4];
#pragma unroll
      for (int gi = 0; gi < 4; ++gi) {
        int col = ul * 4 + gi;
        g[gi] = *(const float*)(arena + col * 512 +
                                (((bl >> 2) ^ (col & 7)) << 4) + (bl & 3) * 4);
      }
      const float4 bs = *(const float4*)(bsum + p0 + ul * 4);
      float si = sigmoidf_(g[0] + bs.x);
      float sf = sigmoidf_(g[1] + bs.y);
      float so = sigmoidf_(g[2] + bs.z);
      float tc = tanhf_(g[3] + bs.w);
      size_t ci = (size_t)(u0 + ul) * NB + bg;
      float cn = sf * c_t[ci] + si * tc;
      float h = so * tanhf_(cn);
      c_t[ci] = cn;
      hv[j] = (short)f2bf(h);
      if (emit) yacc += h * Wout[u0 + ul];
    }
    *(short8*)(hout + (size_t)bg * NH + u0 + ug * 8) = hv;  // 16B store
    if (emit) ypart[((size_t)(t - 127) * 256 + cs * 2 + ug) * NB + bg] = yacc;
  }
}

// ---- y[b][j] = bout + sum_{s<256} ypart[j][s][b]
__global__ __launch_bounds__(256) void wl_finy(const float* __restrict__ ypart,
                                               const float* __restrict__ bout,
                                               float* __restrict__ out) {
  int j = blockIdx.x;
  int b = threadIdx.x;
  const float* yp = ypart + (size_t)j * 256 * NB;
  float s = bout[0];
#pragma unroll 8
  for (int i = 0; i < 256; ++i) s += yp[i * NB + b];
  out[b * NO + j] = s;
}

extern "C" void kernel_launch(void* const* d_in, const int* in_sizes, int n_in,
                              void* d_out, int out_size, void* d_ws, size_t ws_size,
                              hipStream_t stream) {
  const float* trains = (const float*)d_in[0];
  const float* dec    = (const float*)d_in[1];
  const float* Wx     = (const float*)d_in[2];
  const float* bx     = (const float*)d_in[3];
  const float* Wh     = (const float*)d_in[4];
  const float* bh     = (const float*)d_in[5];
  const float* Win    = (const float*)d_in[6];
  const float* b_in   = (const float*)d_in[7];
  const float* Wout   = (const float*)d_in[8];
  const float* bout   = (const float*)d_in[9];
  float* out = (float*)d_out;
  char* ws = (char*)d_ws;

  u16*   Wp    = (u16*)(ws);                  // 34,603,008
  float* bsum  = (float*)(ws + 34603008);     //     32,768
  u16*   xall  = (u16*)(ws + 34635776);       //  4,947,968 -> 39,583,744
  u16*   hcat  = (u16*)(ws + 39583744);       //  4,194,304 -> 43,778,048
  float* c_t   = (float*)(ws + 43778048);     //  2,097,152 -> 45,875,200
  float* ypart = (float*)(ws + 45875200);     //  6,291,456 -> 52,166,656

  // zero hcat (both bufs) + c_t in one contiguous memset
  (void)hipMemsetAsync(ws + 39583744, 0, 6291456, stream);
  wl_pack_w<<<dim3(128, 33), 256, 0, stream>>>(Wx, Wh, Wp);
  wl_bsum<<<32, 256, 0, stream>>>(bx, bh, bsum);
  wl_xall<<<(NSTEPS * NB * NI) / 256, 256, 0, stream>>>(trains, dec, Win, b_in, xall);
  for (int t = 0; t < NSTEPS; ++t)
    wl_step<<<256, 256, 0, stream>>>(Wp, bsum, xall, hcat, c_t, ypart, Wout, t);
  wl_finy<<<NO, 256, 0, stream>>>(ypart, bout, out);
}

// Round 11
// 5211.432 us; speedup vs baseline: 1.4465x; 1.4465x over previous
//
#include <hip/hip_runtime.h>

// WeatherLSTM: B=256, T=128, I=64, H=2048, O=24
// R11: DMA-free GEMM. All operands pre-packed in MFMA fragment layout so each
// fragment is a contiguous 1KB coalesced plain load (global_load_dwordx4,
// 63-deep queue, full L2/L3 rate). K-loop fully unrolled, zero barriers, zero
// LDS (LDS only for epilogue gate transpose). Rationale: R5/R7/R9 all pinned
// at ~18us/step == 792 global_load_lds x ~50cy issue rate; plain loads avoid
// that path entirely.
//
// Layouts (16B fragment per lane; lane: row/col = l&31, k-half = l>>5):
//   Wf[cs 128][cb 2][kc 132][lane 64]  : col = cs*64+cb*32+(l&31), k = kc*16+(l>>5)*8
//   hf[par 2][rb 8][kc 128][lane 64]   : row = rb*32+(l&31),       k = kc*16+(l>>5)*8
//   xf[t 151][rb 8][kc 4][lane 64]     : same, k over the 64-wide x range

#define NB 256
#define NH 2048
#define NI 64
#define NK 2112
#define NPK 8192
#define NSTEPS 151
#define NO 24

typedef __bf16 bf16x8 __attribute__((ext_vector_type(8)));
typedef short short8 __attribute__((ext_vector_type(8)));
typedef float f32x4 __attribute__((ext_vector_type(4)));
typedef float f32x16 __attribute__((ext_vector_type(16)));
typedef unsigned short u16;

__device__ __forceinline__ u16 f2bf(float f) {
  union { float f; unsigned u; } v; v.f = f;
  unsigned r = v.u + 0x7FFFu + ((v.u >> 16) & 1u);  // RNE
  return (u16)(r >> 16);
}

__device__ __forceinline__ float sigmoidf_(float x) { return 1.f / (1.f + __expf(-x)); }
__device__ __forceinline__ float tanhf_(float x) {
  x = fminf(15.f, fmaxf(-15.f, x));
  float e = __expf(2.f * x);
  return (e - 1.f) / (e + 1.f);
}

// ---- pack [Wh;Wx] fp32 [k][4H] -> Wf fragment layout (bf16)
__global__ __launch_bounds__(256) void wl_pack_w(const float* __restrict__ Wx,
                                                 const float* __restrict__ Wh,
                                                 u16* __restrict__ Wf) {
  __shared__ float s[64][65];
  const int j0 = blockIdx.x * 64, k0 = blockIdx.y * 64;
  const int tid = threadIdx.x;
  const int jl = tid & 63, kg = tid >> 6;  // kg 0..3
#pragma unroll
  for (int it = 0; it < 16; ++it) {
    int kl = it * 4 + kg;
    int k = k0 + kl, j = j0 + jl;
    float v = (k < NH) ? Wh[(size_t)k * NPK + j] : Wx[(size_t)(k - NH) * NPK + j];
    s[kl][jl] = v;
  }
  __syncthreads();
  const int j = j0 + jl;
  const int p = (j & (NH - 1)) * 4 + (j >> 11);  // u*4 + gate
  const int cs = p >> 6, cb = (p >> 5) & 1, pl = p & 31;
  const int kc = (k0 >> 4) + kg;                 // 16-k chunk, 0..131
  short8 v0, v1;
#pragma unroll
  for (int e = 0; e < 8; ++e) {
    v0[e] = (short)f2bf(s[kg * 16 + e][jl]);      // k-half 0
    v1[e] = (short)f2bf(s[kg * 16 + 8 + e][jl]);  // k-half 1
  }
  u16* base = Wf + (size_t)(((cs * 2 + cb) * 132 + kc) * 64) * 8;
  *(short8*)(base + (size_t)pl * 8) = v0;         // lane pl
  *(short8*)(base + (size_t)(32 + pl) * 8) = v1;  // lane 32+pl
}

// ---- bsum[p] = bx[j] + bh[j]
__global__ __launch_bounds__(256) void wl_bsum(const float* __restrict__ bx,
                                               const float* __restrict__ bh,
                                               float* __restrict__ bsum) {
  int p = blockIdx.x * 256 + threadIdx.x;
  int j = (p & 3) * NH + (p >> 2);
  bsum[p] = bx[j] + bh[j];
}

// ---- xf fragment layout: encoder = trains, decoder = dec*Win + b_in
__global__ __launch_bounds__(256) void wl_xall(const float* __restrict__ trains,
                                               const float* __restrict__ dec,
                                               const float* __restrict__ Win,
                                               const float* __restrict__ b_in,
                                               u16* __restrict__ xf) {
  int idx = blockIdx.x * 256 + threadIdx.x;
  int i = idx & 63;
  int b = (idx >> 6) & 255;
  int t = idx >> 14;
  float v;
  if (t < 128) v = trains[((size_t)b * 128 + t) * 64 + i];
  else         v = dec[b * 23 + (t - 128)] * Win[i] + b_in[i];
  size_t di = ((((size_t)t * 8 + (b >> 5)) * 4 + (i >> 4)) * 64 +
               ((i >> 3) & 1) * 32 + (b & 31)) * 8 + (i & 7);
  xf[di] = f2bf(v);
}

// ---- one step. 256 blocks x 256 threads (4 waves 2x2). Tile 128 rows x 64 p.
// cs = (bid&7)*16 + ((bid>>3)&15), rh = bid>>7. Wave (wm,wn): rows
// [b0+wm*64,+64) x pcols [p0+wn*32,+32). mfma_32x32x16, all-register k-loop.
__global__ __launch_bounds__(256, 1) void wl_step(const u16* __restrict__ Wf,
                                                  const float* __restrict__ bsum,
                                                  const u16* __restrict__ xf,
                                                  u16* __restrict__ hf,    // 2 bufs
                                                  float* __restrict__ c_t, // [u][b]
                                                  float* __restrict__ ypart,
                                                  const float* __restrict__ Wout,
                                                  int t) {
  __shared__ char arena[32768];  // epilogue gtile only

  const int bid = blockIdx.x;
  const int cs = (bid & 7) * 16 + ((bid >> 3) & 15);  // col-slice 0..127
  const int rh = bid >> 7;                            // row half 0/1
  const int p0 = cs * 64, u0 = cs * 16, b0 = rh * 128;

  const int tid = threadIdx.x;
  const int wv = tid >> 6, lane = tid & 63;           // wv 0..3
  const int wm = wv >> 1, wn = wv & 1;
  const int l31 = lane & 31, lh = lane >> 5;

  const u16* __restrict__ hin = hf + (size_t)(t & 1) * (NB * NH);
  u16* __restrict__ hout = hf + (size_t)((t + 1) & 1) * (NB * NH);

  const int rbg = rh * 4 + wm * 2;                    // first of 2 row-blocks
  // per-lane fragment base pointers (u16 units)
  const u16* const ha0 = hin + ((size_t)(rbg * 128) * 64 + lane) * 8;        // + kc*512
  const u16* const ha1 = hin + ((size_t)((rbg + 1) * 128) * 64 + lane) * 8;
  const u16* const xa0 = xf + ((((size_t)t * 8 + rbg) * 4) * 64 + lane) * 8; // + s*512
  const u16* const xa1 = xf + ((((size_t)t * 8 + rbg + 1) * 4) * 64 + lane) * 8;
  const u16* const wb  = Wf + (((size_t)(cs * 2 + wn) * 132) * 64 + lane) * 8; // + kc*512

  f32x16 acc0 = {}, acc1 = {};

#pragma unroll
  for (int kt = 0; kt < 33; ++kt) {
#pragma unroll
    for (int s = 0; s < 4; ++s) {
      bf16x8 A0, A1, Bf;
      if (kt < 32) {
        const int kc = kt * 4 + s;
        A0 = *(const bf16x8*)(ha0 + (size_t)kc * 512);
        A1 = *(const bf16x8*)(ha1 + (size_t)kc * 512);
        Bf = *(const bf16x8*)(wb + (size_t)kc * 512);
      } else {
        A0 = *(const bf16x8*)(xa0 + (size_t)s * 512);
        A1 = *(const bf16x8*)(xa1 + (size_t)s * 512);
        Bf = *(const bf16x8*)(wb + (size_t)(128 + s) * 512);
      }
      acc0 = __builtin_amdgcn_mfma_f32_32x32x16_bf16(A0, Bf, acc0, 0, 0, 0);
      acc1 = __builtin_amdgcn_mfma_f32_32x32x16_bf16(A1, Bf, acc1, 0, 0, 0);
    }
  }

  // ---- spill acc -> gtile [col 0..63][chunk(row>>2) 0..31] swizzled, 32KB
  {
    const int col = wn * 32 + l31;
#pragma unroll
    for (int mb = 0; mb < 2; ++mb) {
      const f32x16& a = mb ? acc1 : acc0;
#pragma unroll
      for (int q = 0; q < 4; ++q) {
        f32x4 v = {a[q * 4 + 0], a[q * 4 + 1], a[q * 4 + 2], a[q * 4 + 3]};
        int chunk = wm * 16 + mb * 8 + q * 2 + lh;  // row>>2
        *(f32x4*)(arena + col * 512 + ((chunk ^ (col & 7)) << 4)) = v;
      }
    }
  }
  __syncthreads();

  // ---- gates + state: thread -> (row bl 0..127, unit-group ug of 8 units)
  {
    const int bl = tid & 127, ug = tid >> 7;  // ug 0..1
    const int bg = b0 + bl;
    const bool emit = (t >= 127);
    float yacc = 0.f;
    short8 hv;
#pragma unroll
    for (int j = 0; j < 8; ++j) {
      int ul = ug * 8 + j;                 // local unit 0..15
      float g[4];
#pragma unroll
      for (int gi = 0; gi < 4; ++gi) {
        int col = ul * 4 + gi;
        g[gi] = *(const float*)(arena + col * 512 +
                                (((bl >> 2) ^ (col & 7)) << 4) + (bl & 3) * 4);
      }
      const float4 bs = *(const float4*)(bsum + p0 + ul * 4);
      float si = sigmoidf_(g[0] + bs.x);
      float sf = sigmoidf_(g[1] + bs.y);
      float so = sigmoidf_(g[2] + bs.z);
      float tc = tanhf_(g[3] + bs.w);
      size_t ci = (size_t)(u0 + ul) * NB + bg;
      float cn = sf * c_t[ci] + si * tc;
      float h = so * tanhf_(cn);
      c_t[ci] = cn;
      hv[j] = (short)f2bf(h);
      if (emit) yacc += h * Wout[u0 + ul];
    }
    // write h directly in fragment layout: hf[par^1][bg>>5][kc=cs][ug*32+(bg&31)]
    *(short8*)(hout + (((size_t)(bg >> 5) * 128 + cs) * 64 + ug * 32 + (bg & 31)) * 8) = hv;
    if (emit) ypart[((size_t)(t - 127) * 256 + cs * 2 + ug) * NB + bg] = yacc;
  }
}

// ---- y[b][j] = bout + sum_{s<256} ypart[j][s][b]
__global__ __launch_bounds__(256) void wl_finy(const float* __restrict__ ypart,
                                               const float* __restrict__ bout,
                                               float* __restrict__ out) {
  int j = blockIdx.x;
  int b = threadIdx.x;
  const float* yp = ypart + (size_t)j * 256 * NB;
  float s = bout[0];
#pragma unroll 8
  for (int i = 0; i < 256; ++i) s += yp[i * NB + b];
  out[b * NO + j] = s;
}

extern "C" void kernel_launch(void* const* d_in, const int* in_sizes, int n_in,
                              void* d_out, int out_size, void* d_ws, size_t ws_size,
                              hipStream_t stream) {
  const float* trains = (const float*)d_in[0];
  const float* dec    = (const float*)d_in[1];
  const float* Wx     = (const float*)d_in[2];
  const float* bx     = (const float*)d_in[3];
  const float* Wh     = (const float*)d_in[4];
  const float* bh     = (const float*)d_in[5];
  const float* Win    = (const float*)d_in[6];
  const float* b_in   = (const float*)d_in[7];
  const float* Wout   = (const float*)d_in[8];
  const float* bout   = (const float*)d_in[9];
  float* out = (float*)d_out;
  char* ws = (char*)d_ws;

  u16*   Wf    = (u16*)(ws);                  // 34,603,008
  float* bsum  = (float*)(ws + 34603008);     //     32,768
  u16*   xf    = (u16*)(ws + 34635776);       //  4,947,968 -> 39,583,744
  u16*   hf    = (u16*)(ws + 39583744);       //  2,097,152 -> 41,680,896 (2 bufs)
  float* c_t   = (float*)(ws + 41680896);     //  2,097,152 -> 43,778,048
  float* ypart = (float*)(ws + 43778048);     //  6,291,456 -> 50,069,504

  // zero hf (both bufs) + c_t in one contiguous memset
  (void)hipMemsetAsync(ws + 39583744, 0, 4194304, stream);
  wl_pack_w<<<dim3(128, 33), 256, 0, stream>>>(Wx, Wh, Wf);
  wl_bsum<<<32, 256, 0, stream>>>(bx, bh, bsum);
  wl_xall<<<(NSTEPS * NB * NI) / 256, 256, 0, stream>>>(trains, dec, Win, b_in, xf);
  for (int t = 0; t < NSTEPS; ++t)
    wl_step<<<256, 256, 0, stream>>>(Wf, bsum, xf, hf, c_t, ypart, Wout, t);
  wl_finy<<<NO, 256, 0, stream>>>(ypart, bout, out);
}

// Round 12
// 2892.576 us; speedup vs baseline: 2.6061x; 1.8017x over previous
//
#include <hip/hip_runtime.h>

// WeatherLSTM: B=256, T=128, I=64, H=2048, O=24
// R12: hybrid dataflow. B (weights, dedup-critical) -> global_load_lds DMA,
// only 264 DMA instr/CU/step (the measured ~50cy/instr wall -> ~5.5us).
// A (activations) -> plain coalesced register loads from fragment-layout
// hf/xf (R11 machinery) on the independent vector-return path, fully deduped
// by a 4x1 wave grid (wave = 32 rows x 64 cols). 4 B-buffers, raw s_barrier,
// counted vmcnt over the interleaved issue stream, k-loop fully unrolled.

#define NB 256
#define NH 2048
#define NI 64
#define NK 2112
#define NPK 8192
#define NSTEPS 151
#define NO 24

typedef __bf16 bf16x8 __attribute__((ext_vector_type(8)));
typedef short short8 __attribute__((ext_vector_type(8)));
typedef float f32x4 __attribute__((ext_vector_type(4)));
typedef float f32x16 __attribute__((ext_vector_type(16)));
typedef unsigned short u16;

__device__ __forceinline__ u16 f2bf(float f) {
  union { float f; unsigned u; } v; v.f = f;
  unsigned r = v.u + 0x7FFFu + ((v.u >> 16) & 1u);  // RNE
  return (u16)(r >> 16);
}

__device__ __forceinline__ void gload16(const void* g, void* l) {
  __builtin_amdgcn_global_load_lds(
      (const __attribute__((address_space(1))) unsigned int*)g,
      (__attribute__((address_space(3))) unsigned int*)l, 16, 0, 0);
}

__device__ __forceinline__ float sigmoidf_(float x) { return 1.f / (1.f + __expf(-x)); }
__device__ __forceinline__ float tanhf_(float x) {
  x = fminf(15.f, fmaxf(-15.f, x));
  float e = __expf(2.f * x);
  return (e - 1.f) / (e + 1.f);
}

// ---- pack [Wh;Wx] fp32 [k][4H] -> Wp bf16 [p][k], p = u*4+g  (R7-proven)
__global__ __launch_bounds__(256) void wl_pack_w(const float* __restrict__ Wx,
                                                 const float* __restrict__ Wh,
                                                 u16* __restrict__ Wp) {
  __shared__ float s[64][65];
  const int j0 = blockIdx.x * 64, k0 = blockIdx.y * 64;
  const int tid = threadIdx.x;
  const int jl = tid & 63, kg = tid >> 6;
#pragma unroll
  for (int it = 0; it < 16; ++it) {
    int kl = it * 4 + kg;
    int k = k0 + kl, j = j0 + jl;
    float v = (k < NH) ? Wh[(size_t)k * NPK + j] : Wx[(size_t)(k - NH) * NPK + j];
    s[kl][jl] = v;
  }
  __syncthreads();
  int j = j0 + jl;
  int p = (j & (NH - 1)) * 4 + (j >> 11);
  short8 v0, v1;
#pragma unroll
  for (int e = 0; e < 8; ++e) {
    v0[e] = (short)f2bf(s[kg * 16 + e][jl]);
    v1[e] = (short)f2bf(s[kg * 16 + 8 + e][jl]);
  }
  short8* dst = (short8*)(Wp + (size_t)p * NK + k0 + kg * 16);
  dst[0] = v0;
  dst[1] = v1;
}

__global__ __launch_bounds__(256) void wl_bsum(const float* __restrict__ bx,
                                               const float* __restrict__ bh,
                                               float* __restrict__ bsum) {
  int p = blockIdx.x * 256 + threadIdx.x;
  int j = (p & 3) * NH + (p >> 2);
  bsum[p] = bx[j] + bh[j];
}

// ---- xf fragment layout (R11-proven): lane = k-half*32 + row31, elem = k&7
__global__ __launch_bounds__(256) void wl_xall(const float* __restrict__ trains,
                                               const float* __restrict__ dec,
                                               const float* __restrict__ Win,
                                               const float* __restrict__ b_in,
                                               u16* __restrict__ xf) {
  int idx = blockIdx.x * 256 + threadIdx.x;
  int i = idx & 63;
  int b = (idx >> 6) & 255;
  int t = idx >> 14;
  float v;
  if (t < 128) v = trains[((size_t)b * 128 + t) * 64 + i];
  else         v = dec[b * 23 + (t - 128)] * Win[i] + b_in[i];
  size_t di = ((((size_t)t * 8 + (b >> 5)) * 4 + (i >> 4)) * 64 +
               ((i >> 3) & 1) * 32 + (b & 31)) * 8 + (i & 7);
  xf[di] = f2bf(v);
}

// ---- one step. 256 blocks x 256 threads (4 waves, 4x1). Tile 128 x 64 p.
// cs = (bid&7)*16 + ((bid>>3)&15), rh = bid>>7. Wave wv: rows
// [b0+wv*32,+32) x all 64 pcols. mfma_32x32x16.
__global__ __launch_bounds__(256, 1) void wl_step(const u16* __restrict__ Wpg,
                                                  const float* __restrict__ bsum,
                                                  const u16* __restrict__ xf,
                                                  u16* __restrict__ hf,    // 2 bufs
                                                  float* __restrict__ c_t, // [u][b]
                                                  float* __restrict__ ypart,
                                                  const float* __restrict__ Wout,
                                                  int t) {
  __shared__ char arena[65536];  // B bufs 4 x 8KB | gtile 32KB @32768

  const int bid = blockIdx.x;
  const int cs = (bid & 7) * 16 + ((bid >> 3) & 15);  // col-slice 0..127
  const int rh = bid >> 7;                            // row half 0/1
  const int p0 = cs * 64, u0 = cs * 16, b0 = rh * 128;

  const int tid = threadIdx.x;
  const int wv = tid >> 6, lane = tid & 63;           // wv 0..3
  const int l31 = lane & 31, lh = lane >> 5;
  const int srow = lane >> 3, sc = lane & 7;
  const int g8 = sc ^ srow;                           // pre-swizzled chunk

  const u16* __restrict__ hin = hf + (size_t)(t & 1) * (NB * NH);
  u16* __restrict__ hout = hf + (size_t)((t + 1) & 1) * (NB * NH);

  const int rbg = rh * 4 + wv;                        // this wave's 32-row block
  const u16* const ha = hin + ((size_t)(rbg * 128) * 64 + lane) * 8;          // +kc*512
  const u16* const xa = xf + ((((size_t)t * 8 + rbg) * 4) * 64 + lane) * 8;   // +s*512
  const u16* const bsrc0 = Wpg + (size_t)p0 * NK;

  f32x16 acc0 = {}, acc1 = {};
  bf16x8 A[3][4];

  auto stageB = [&](int kt, int buf) {
    char* const base = arena + buf * 8192;
    const u16* bsrc = bsrc0 + (size_t)kt * 64;
#pragma unroll
    for (int i = 0; i < 2; ++i) {
      int qb = wv * 2 + i;                 // 1KB chunk 0..7
      int col = qb * 8 + srow;             // 0..63
      gload16(bsrc + (size_t)col * NK + g8 * 8, base + qb * 1024);
    }
  };
  auto loadA = [&](int kt, bf16x8* dst) {
    if (kt < 32) {
#pragma unroll
      for (int s = 0; s < 4; ++s)
        dst[s] = *(const bf16x8*)(ha + (size_t)(kt * 4 + s) * 512);
    } else {
#pragma unroll
      for (int s = 0; s < 4; ++s)
        dst[s] = *(const bf16x8*)(xa + (size_t)s * 512);
    }
  };
  auto compute = [&](int buf, bf16x8* a) {
    const char* Bb = arena + buf * 8192;
#pragma unroll
    for (int s = 0; s < 4; ++s) {
      const int c8 = s * 2 + lh;
      const int col0 = l31, col1 = 32 + l31;
      bf16x8 b0 = *(const bf16x8*)(Bb + col0 * 128 + ((c8 ^ (col0 & 7)) << 4));
      bf16x8 b1 = *(const bf16x8*)(Bb + col1 * 128 + ((c8 ^ (col1 & 7)) << 4));
      acc0 = __builtin_amdgcn_mfma_f32_32x32x16_bf16(a[s], b0, acc0, 0, 0, 0);
      acc1 = __builtin_amdgcn_mfma_f32_32x32x16_bf16(a[s], b1, acc1, 0, 0, 0);
    }
  };

  // prologue: B(0),B(1) staged; A(0),A(1) in flight (12 vm-ops)
  stageB(0, 0); stageB(1, 1);
  loadA(0, A[0]); loadA(1, A[1]);
#pragma unroll
  for (int kt = 0; kt < 33; ++kt) {
    if (kt + 2 <= 32) {
      stageB(kt + 2, (kt + 2) & 3);        // 2 ops
      loadA(kt + 2, A[(kt + 2) % 3]);      // 4 ops
    }
    // per-wave vm queue: [B(kt+2)2, A(kt+2)4, B(kt+1)2, A(kt+1)4, ...]
    if (kt <= 30)      asm volatile("s_waitcnt vmcnt(12)" ::: "memory");
    else if (kt == 31) asm volatile("s_waitcnt vmcnt(6)" ::: "memory");
    else               asm volatile("s_waitcnt vmcnt(0)" ::: "memory");
    asm volatile("s_barrier" ::: "memory");  // B(kt) visible to all waves; all
                                             // waves past compute(kt-2) (buf safe)
    compute(kt & 3, A[kt % 3]);
  }

  // ---- spill acc -> gtile [col 0..63][chunk(row>>2) 0..31] swizzled (32KB)
  __syncthreads();
  {
    char* const gt = arena + 32768;
#pragma unroll
    for (int cb = 0; cb < 2; ++cb) {
      const f32x16& a = cb ? acc1 : acc0;
      const int col = cb * 32 + l31;
#pragma unroll
      for (int q = 0; q < 4; ++q) {
        f32x4 v = {a[q * 4 + 0], a[q * 4 + 1], a[q * 4 + 2], a[q * 4 + 3]};
        int chunk = wv * 8 + q * 2 + lh;   // row>>2 ; row = wv*32 + q*8 + lh*4
        *(f32x4*)(gt + col * 512 + ((chunk ^ (col & 7)) << 4)) = v;
      }
    }
  }
  __syncthreads();

  // ---- gates + state: thread -> (row bl 0..127, unit-group ug of 8 units)
  {
    const char* const gt = arena + 32768;
    const int bl = tid & 127, ug = tid >> 7;  // ug 0..1
    const int bg = b0 + bl;
    const bool emit = (t >= 127);
    float yacc = 0.f;
    short8 hv;
#pragma unroll
    for (int j = 0; j < 8; ++j) {
      int ul = ug * 8 + j;                 // local unit 0..15
      float g[4];
#pragma unroll
      for (int gi = 0; gi < 4; ++gi) {
        int col = ul * 4 + gi;
        g[gi] = *(const float*)(gt + col * 512 +
                                (((bl >> 2) ^ (col & 7)) << 4) + (bl & 3) * 4);
      }
      const float4 bs = *(const float4*)(bsum + p0 + ul * 4);
      float si = sigmoidf_(g[0] + bs.x);
      float sf = sigmoidf_(g[1] + bs.y);
      float so = sigmoidf_(g[2] + bs.z);
      float tc = tanhf_(g[3] + bs.w);
      size_t ci = (size_t)(u0 + ul) * NB + bg;
      float cn = sf * c_t[ci] + si * tc;
      float h = so * tanhf_(cn);
      c_t[ci] = cn;
      hv[j] = (short)f2bf(h);
      if (emit) yacc += h * Wout[u0 + ul];
    }
    // h written directly in fragment layout: hf[rb=bg>>5][kc=cs][lane=ug*32+(bg&31)]
    *(short8*)(hout + (((size_t)(bg >> 5) * 128 + cs) * 64 + ug * 32 + (bg & 31)) * 8) = hv;
    if (emit) ypart[((size_t)(t - 127) * 256 + cs * 2 + ug) * NB + bg] = yacc;
  }
}

// ---- y[b][j] = bout + sum_{s<256} ypart[j][s][b]
__global__ __launch_bounds__(256) void wl_finy(const float* __restrict__ ypart,
                                               const float* __restrict__ bout,
                                               float* __restrict__ out) {
  int j = blockIdx.x;
  int b = threadIdx.x;
  const float* yp = ypart + (size_t)j * 256 * NB;
  float s = bout[0];
#pragma unroll 8
  for (int i = 0; i < 256; ++i) s += yp[i * NB + b];
  out[b * NO + j] = s;
}

extern "C" void kernel_launch(void* const* d_in, const int* in_sizes, int n_in,
                              void* d_out, int out_size, void* d_ws, size_t ws_size,
                              hipStream_t stream) {
  const float* trains = (const float*)d_in[0];
  const float* dec    = (const float*)d_in[1];
  const float* Wx     = (const float*)d_in[2];
  const float* bx     = (const float*)d_in[3];
  const float* Wh     = (const float*)d_in[4];
  const float* bh     = (const float*)d_in[5];
  const float* Win    = (const float*)d_in[6];
  const float* b_in   = (const float*)d_in[7];
  const float* Wout   = (const float*)d_in[8];
  const float* bout   = (const float*)d_in[9];
  float* out = (float*)d_out;
  char* ws = (char*)d_ws;

  u16*   Wp    = (u16*)(ws);                  // 34,603,008
  float* bsum  = (float*)(ws + 34603008);     //     32,768
  u16*   xf    = (u16*)(ws + 34635776);       //  4,947,968 -> 39,583,744
  u16*   hf    = (u16*)(ws + 39583744);       //  2,097,152 -> 41,680,896 (2 bufs)
  float* c_t   = (float*)(ws + 41680896);     //  2,097,152 -> 43,778,048
  float* ypart = (float*)(ws + 43778048);     //  6,291,456 -> 50,069,504

  // zero hf (both bufs) + c_t in one contiguous memset
  (void)hipMemsetAsync(ws + 39583744, 0, 4194304, stream);
  wl_pack_w<<<dim3(128, 33), 256, 0, stream>>>(Wx, Wh, Wp);
  wl_bsum<<<32, 256, 0, stream>>>(bx, bh, bsum);
  wl_xall<<<(NSTEPS * NB * NI) / 256, 256, 0, stream>>>(trains, dec, Win, b_in, xf);
  for (int t = 0; t < NSTEPS; ++t)
    wl_step<<<256, 256, 0, stream>>>(Wp, bsum, xf, hf, c_t, ypart, Wout, t);
  wl_finy<<<NO, 256, 0, stream>>>(ypart, bout, out);
}

// Round 13
// 2790.088 us; speedup vs baseline: 2.7019x; 1.0367x over previous
//
#include <hip/hip_runtime.h>

// WeatherLSTM: B=256, T=128, I=64, H=2048, O=24
// R13 = R12 (hybrid: B via LDS-DMA, A via fragment-layout register loads)
// with the pipeline deepened past L3 latency: B staged 4 tiles ahead over
// 6 LDS bufs (coverage ~1200cy > ~900cy L3), A 3 ahead over a 4-reg ring.
// Counted vmcnt ladder re-derived for issue order [B(kt+4)x2, A(kt+3)x4].

#define NB 256
#define NH 2048
#define NI 64
#define NK 2112
#define NPK 8192
#define NSTEPS 151
#define NO 24

typedef __bf16 bf16x8 __attribute__((ext_vector_type(8)));
typedef short short8 __attribute__((ext_vector_type(8)));
typedef float f32x4 __attribute__((ext_vector_type(4)));
typedef float f32x16 __attribute__((ext_vector_type(16)));
typedef unsigned short u16;

__device__ __forceinline__ u16 f2bf(float f) {
  union { float f; unsigned u; } v; v.f = f;
  unsigned r = v.u + 0x7FFFu + ((v.u >> 16) & 1u);  // RNE
  return (u16)(r >> 16);
}

__device__ __forceinline__ void gload16(const void* g, void* l) {
  __builtin_amdgcn_global_load_lds(
      (const __attribute__((address_space(1))) unsigned int*)g,
      (__attribute__((address_space(3))) unsigned int*)l, 16, 0, 0);
}

__device__ __forceinline__ float sigmoidf_(float x) { return 1.f / (1.f + __expf(-x)); }
__device__ __forceinline__ float tanhf_(float x) {
  x = fminf(15.f, fmaxf(-15.f, x));
  float e = __expf(2.f * x);
  return (e - 1.f) / (e + 1.f);
}

// ---- pack [Wh;Wx] fp32 [k][4H] -> Wp bf16 [p][k], p = u*4+g  (R7-proven)
__global__ __launch_bounds__(256) void wl_pack_w(const float* __restrict__ Wx,
                                                 const float* __restrict__ Wh,
                                                 u16* __restrict__ Wp) {
  __shared__ float s[64][65];
  const int j0 = blockIdx.x * 64, k0 = blockIdx.y * 64;
  const int tid = threadIdx.x;
  const int jl = tid & 63, kg = tid >> 6;
#pragma unroll
  for (int it = 0; it < 16; ++it) {
    int kl = it * 4 + kg;
    int k = k0 + kl, j = j0 + jl;
    float v = (k < NH) ? Wh[(size_t)k * NPK + j] : Wx[(size_t)(k - NH) * NPK + j];
    s[kl][jl] = v;
  }
  __syncthreads();
  int j = j0 + jl;
  int p = (j & (NH - 1)) * 4 + (j >> 11);
  short8 v0, v1;
#pragma unroll
  for (int e = 0; e < 8; ++e) {
    v0[e] = (short)f2bf(s[kg * 16 + e][jl]);
    v1[e] = (short)f2bf(s[kg * 16 + 8 + e][jl]);
  }
  short8* dst = (short8*)(Wp + (size_t)p * NK + k0 + kg * 16);
  dst[0] = v0;
  dst[1] = v1;
}

__global__ __launch_bounds__(256) void wl_bsum(const float* __restrict__ bx,
                                               const float* __restrict__ bh,
                                               float* __restrict__ bsum) {
  int p = blockIdx.x * 256 + threadIdx.x;
  int j = (p & 3) * NH + (p >> 2);
  bsum[p] = bx[j] + bh[j];
}

// ---- xf fragment layout (R11-proven): lane = k-half*32 + row31, elem = k&7
__global__ __launch_bounds__(256) void wl_xall(const float* __restrict__ trains,
                                               const float* __restrict__ dec,
                                               const float* __restrict__ Win,
                                               const float* __restrict__ b_in,
                                               u16* __restrict__ xf) {
  int idx = blockIdx.x * 256 + threadIdx.x;
  int i = idx & 63;
  int b = (idx >> 6) & 255;
  int t = idx >> 14;
  float v;
  if (t < 128) v = trains[((size_t)b * 128 + t) * 64 + i];
  else         v = dec[b * 23 + (t - 128)] * Win[i] + b_in[i];
  size_t di = ((((size_t)t * 8 + (b >> 5)) * 4 + (i >> 4)) * 64 +
               ((i >> 3) & 1) * 32 + (b & 31)) * 8 + (i & 7);
  xf[di] = f2bf(v);
}

// ---- one step. 256 blocks x 256 threads (4 waves, 4x1). Tile 128 x 64 p.
// cs = (bid&7)*16 + ((bid>>3)&15), rh = bid>>7. Wave wv: rows
// [b0+wv*32,+32) x all 64 pcols. mfma_32x32x16.
__global__ __launch_bounds__(256, 1) void wl_step(const u16* __restrict__ Wpg,
                                                  const float* __restrict__ bsum,
                                                  const u16* __restrict__ xf,
                                                  u16* __restrict__ hf,    // 2 bufs
                                                  float* __restrict__ c_t, // [u][b]
                                                  float* __restrict__ ypart,
                                                  const float* __restrict__ Wout,
                                                  int t) {
  __shared__ char arena[81920];  // B bufs 6 x 8KB | gtile 32KB @49152

  const int bid = blockIdx.x;
  const int cs = (bid & 7) * 16 + ((bid >> 3) & 15);  // col-slice 0..127
  const int rh = bid >> 7;                            // row half 0/1
  const int p0 = cs * 64, u0 = cs * 16, b0 = rh * 128;

  const int tid = threadIdx.x;
  const int wv = tid >> 6, lane = tid & 63;           // wv 0..3
  const int l31 = lane & 31, lh = lane >> 5;
  const int srow = lane >> 3, sc = lane & 7;
  const int g8 = sc ^ srow;                           // pre-swizzled chunk

  const u16* __restrict__ hin = hf + (size_t)(t & 1) * (NB * NH);
  u16* __restrict__ hout = hf + (size_t)((t + 1) & 1) * (NB * NH);

  const int rbg = rh * 4 + wv;                        // this wave's 32-row block
  const u16* const ha = hin + ((size_t)(rbg * 128) * 64 + lane) * 8;          // +kc*512
  const u16* const xa = xf + ((((size_t)t * 8 + rbg) * 4) * 64 + lane) * 8;   // +s*512
  const u16* const bsrc0 = Wpg + (size_t)p0 * NK;

  f32x16 acc0 = {}, acc1 = {};
  bf16x8 A[4][4];

  auto stageB = [&](int kt, int buf) {
    char* const base = arena + buf * 8192;
    const u16* bsrc = bsrc0 + (size_t)kt * 64;
#pragma unroll
    for (int i = 0; i < 2; ++i) {
      int qb = wv * 2 + i;                 // 1KB chunk 0..7
      int col = qb * 8 + srow;             // 0..63
      gload16(bsrc + (size_t)col * NK + g8 * 8, base + qb * 1024);
    }
  };
  auto loadA = [&](int kt, bf16x8* dst) {
    if (kt < 32) {
#pragma unroll
      for (int s = 0; s < 4; ++s)
        dst[s] = *(const bf16x8*)(ha + (size_t)(kt * 4 + s) * 512);
    } else {
#pragma unroll
      for (int s = 0; s < 4; ++s)
        dst[s] = *(const bf16x8*)(xa + (size_t)s * 512);
    }
  };
  auto compute = [&](int buf, bf16x8* a) {
    const char* Bb = arena + buf * 8192;
#pragma unroll
    for (int s = 0; s < 4; ++s) {
      const int c8 = s * 2 + lh;
      const int col0 = l31, col1 = 32 + l31;
      bf16x8 b0 = *(const bf16x8*)(Bb + col0 * 128 + ((c8 ^ (col0 & 7)) << 4));
      bf16x8 b1 = *(const bf16x8*)(Bb + col1 * 128 + ((c8 ^ (col1 & 7)) << 4));
      acc0 = __builtin_amdgcn_mfma_f32_32x32x16_bf16(a[s], b0, acc0, 0, 0, 0);
      acc1 = __builtin_amdgcn_mfma_f32_32x32x16_bf16(a[s], b1, acc1, 0, 0, 0);
    }
  };

  // prologue, ordered as virtual iters -4..-1:
  // [B0] [B1 A0] [B2 A1] [B3 A2]
  stageB(0, 0);
  stageB(1, 1); loadA(0, A[0]);
  stageB(2, 2); loadA(1, A[1]);
  stageB(3, 3); loadA(2, A[2]);
#pragma unroll
  for (int kt = 0; kt < 33; ++kt) {
    if (kt + 4 <= 32) stageB(kt + 4, (kt + 4) % 6);      // 2 ops
    if (kt + 3 <= 32) loadA(kt + 3, A[(kt + 3) & 3]);    // 4 ops
    // outstanding after A(kt) (issued at iter kt-3): iters kt-2..kt
    if (kt <= 28)      asm volatile("s_waitcnt vmcnt(18)" ::: "memory");
    else if (kt == 29) asm volatile("s_waitcnt vmcnt(16)" ::: "memory");
    else if (kt == 30) asm volatile("s_waitcnt vmcnt(10)" ::: "memory");
    else if (kt == 31) asm volatile("s_waitcnt vmcnt(4)" ::: "memory");
    else               asm volatile("s_waitcnt vmcnt(0)" ::: "memory");
    asm volatile("s_barrier" ::: "memory");  // B(kt) (all waves' chunks) in LDS;
                                             // all waves past compute(kt-1)
    compute(kt % 6, A[kt & 3]);
  }

  // ---- spill acc -> gtile [col 0..63][chunk(row>>2) 0..31] swizzled (32KB)
  __syncthreads();
  {
    char* const gt = arena + 49152;
#pragma unroll
    for (int cb = 0; cb < 2; ++cb) {
      const f32x16& a = cb ? acc1 : acc0;
      const int col = cb * 32 + l31;
#pragma unroll
      for (int q = 0; q < 4; ++q) {
        f32x4 v = {a[q * 4 + 0], a[q * 4 + 1], a[q * 4 + 2], a[q * 4 + 3]};
        int chunk = wv * 8 + q * 2 + lh;   // row>>2 ; row = wv*32 + q*8 + lh*4
        *(f32x4*)(gt + col * 512 + ((chunk ^ (col & 7)) << 4)) = v;
      }
    }
  }
  __syncthreads();

  // ---- gates + state: thread -> (row bl 0..127, unit-group ug of 8 units)
  {
    const char* const gt = arena + 49152;
    const int bl = tid & 127, ug = tid >> 7;  // ug 0..1
    const int bg = b0 + bl;
    const bool emit = (t >= 127);
    float yacc = 0.f;
    short8 hv;
#pragma unroll
    for (int j = 0; j < 8; ++j) {
      int ul = ug * 8 + j;                 // local unit 0..15
      float g[4];
#pragma unroll
      for (int gi = 0; gi < 4; ++gi) {
        int col = ul * 4 + gi;
        g[gi] = *(const float*)(gt + col * 512 +
                                (((bl >> 2) ^ (col & 7)) << 4) + (bl & 3) * 4);
      }
      const float4 bs = *(const float4*)(bsum + p0 + ul * 4);
      float si = sigmoidf_(g[0] + bs.x);
      float sf = sigmoidf_(g[1] + bs.y);
      float so = sigmoidf_(g[2] + bs.z);
      float tc = tanhf_(g[3] + bs.w);
      size_t ci = (size_t)(u0 + ul) * NB + bg;
      float cn = sf * c_t[ci] + si * tc;
      float h = so * tanhf_(cn);
      c_t[ci] = cn;
      hv[j] = (short)f2bf(h);
      if (emit) yacc += h * Wout[u0 + ul];
    }
    // h written directly in fragment layout: hf[rb=bg>>5][kc=cs][lane=ug*32+(bg&31)]
    *(short8*)(hout + (((size_t)(bg >> 5) * 128 + cs) * 64 + ug * 32 + (bg & 31)) * 8) = hv;
    if (emit) ypart[((size_t)(t - 127) * 256 + cs * 2 + ug) * NB + bg] = yacc;
  }
}

// ---- y[b][j] = bout + sum_{s<256} ypart[j][s][b]
__global__ __launch_bounds__(256) void wl_finy(const float* __restrict__ ypart,
                                               const float* __restrict__ bout,
                                               float* __restrict__ out) {
  int j = blockIdx.x;
  int b = threadIdx.x;
  const float* yp = ypart + (size_t)j * 256 * NB;
  float s = bout[0];
#pragma unroll 8
  for (int i = 0; i < 256; ++i) s += yp[i * NB + b];
  out[b * NO + j] = s;
}

extern "C" void kernel_launch(void* const* d_in, const int* in_sizes, int n_in,
                              void* d_out, int out_size, void* d_ws, size_t ws_size,
                              hipStream_t stream) {
  const float* trains = (const float*)d_in[0];
  const float* dec    = (const float*)d_in[1];
  const float* Wx     = (const float*)d_in[2];
  const float* bx     = (const float*)d_in[3];
  const float* Wh     = (const float*)d_in[4];
  const float* bh     = (const float*)d_in[5];
  const float* Win    = (const float*)d_in[6];
  const float* b_in   = (const float*)d_in[7];
  const float* Wout   = (const float*)d_in[8];
  const float* bout   = (const float*)d_in[9];
  float* out = (float*)d_out;
  char* ws = (char*)d_ws;

  u16*   Wp    = (u16*)(ws);                  // 34,603,008
  float* bsum  = (float*)(ws + 34603008);     //     32,768
  u16*   xf    = (u16*)(ws + 34635776);       //  4,947,968 -> 39,583,744
  u16*   hf    = (u16*)(ws + 39583744);       //  2,097,152 -> 41,680,896 (2 bufs)
  float* c_t   = (float*)(ws + 41680896);     //  2,097,152 -> 43,778,048
  float* ypart = (float*)(ws + 43778048);     //  6,291,456 -> 50,069,504

  // zero hf (both bufs) + c_t in one contiguous memset
  (void)hipMemsetAsync(ws + 39583744, 0, 4194304, stream);
  wl_pack_w<<<dim3(128, 33), 256, 0, stream>>>(Wx, Wh, Wp);
  wl_bsum<<<32, 256, 0, stream>>>(bx, bh, bsum);
  wl_xall<<<(NSTEPS * NB * NI) / 256, 256, 0, stream>>>(trains, dec, Win, b_in, xf);
  for (int t = 0; t < NSTEPS; ++t)
    wl_step<<<256, 256, 0, stream>>>(Wp, bsum, xf, hf, c_t, ypart, Wout, t);
  wl_finy<<<NO, 256, 0, stream>>>(ypart, bout, out);
}